// Round 4
// baseline (340.136 us; speedup 1.0000x reference)
//
#include <hip/hip_runtime.h>
#include <hip/hip_bf16.h>

// Flash-style block attention, MI355X gfx950. Round 8.
// R8 vs R7 (113us, REGRESSION): T15 spilled (WRITE_SIZE +12MB = scratch) ->
// reverted. vs R6 (101us): occupancy was LDS-capped, not reg-capped:
// 2x37888 B double buffer -> 2 WGs/CU = 16 waves (40% meas). R5 proved the
// double buffer hides nothing (TLP covers load latency), so it spends the
// exact resource (LDS) that feeds TLP.
//  - SINGLE 37888 B buffer, 2 barriers/chunk (bar; store; bar), T14 kept:
//    global->reg prefetch issues before compute, convert+ds_write after.
//  - __launch_bounds__(512,6): reg cap 85 >= ~80 used; 37888 B <= 53.3K
//    -> 3 WGs/CU = 24 waves = 75% theoretical occupancy (1.5x TLP).
//  - All R6 wins kept: P single-bf16, exp2 domain, defer-max, deferred
//    l-sum, V hi/lo interleaved (b128), setprio.
// Predicted: dur -> ~80us/dispatch, Occupancy ~60%, VALU ~44%, no scratch.

typedef __attribute__((ext_vector_type(8))) short bf16x8;
typedef __attribute__((ext_vector_type(4))) short bf16x4;
typedef __attribute__((ext_vector_type(4))) float f32x4;

#define MFMA32(A, B, C) __builtin_amdgcn_mfma_f32_16x16x32_bf16((A), (B), (C), 0, 0, 0)
#define MFMA16(A, B, C) __builtin_amdgcn_mfma_f32_16x16x16bf16_1k((A), (B), (C), 0, 0, 0)

__device__ __forceinline__ unsigned int cvt_pk(float a, float b) {
    __hip_bfloat162 h = __float22bfloat162_rn(float2{a, b});
    union { __hip_bfloat162 h; unsigned int u; } c;
    c.h = h;
    return c.u;
}
__device__ __forceinline__ void split2(float a, float b, unsigned int& hi, unsigned int& lo) {
    unsigned int h = cvt_pk(a, b);
    float ra = a - __uint_as_float(h << 16);
    float rb = b - __uint_as_float(h & 0xFFFF0000u);
    hi = h;
    lo = cvt_pk(ra, rb);
}
__device__ __forceinline__ void split8v(f32x4 a, f32x4 b, bf16x8& hi, bf16x8& lo) {
    union { bf16x8 v; unsigned int w[4]; } H, L;
    split2(a[0], a[1], H.w[0], L.w[0]);
    split2(a[2], a[3], H.w[1], L.w[1]);
    split2(b[0], b[1], H.w[2], L.w[2]);
    split2(b[2], b[3], H.w[3], L.w[3]);
    hi = H.v; lo = L.v;
}

// Buffer layout: K_hi [64][72] (9216 B) | K_lo [64][72] (9216 B) |
// V^T interleaved [64][152 halfwords] (19456 B). Total 37888 B.
// Epilogue reuses bytes [0,34816) as [128][68] f32.
#define BUF_BYTES 37888

#define LOG2E 1.44269504f
#define QSCALE 0.180336880f  /* 0.125 * log2(e) */
#define DEFER_THR 8.0f

__global__ __launch_bounds__(512, 6) void block_attn_kernel(
    const float* __restrict__ q, const float* __restrict__ k,
    const float* __restrict__ v, const float* __restrict__ amask,
    const float* __restrict__ gk, const float* __restrict__ gv,
    const float* __restrict__ gmask, float* __restrict__ out) {
    constexpr int Hh = 16, Tt = 4096, Gg = 128;

    __shared__ __align__(16) unsigned char lds[BUF_BYTES];
    float* o_scr = (float*)lds;  // [128][68] epilogue scratch

    const int blk = blockIdx.x;
    const int bh  = blockIdx.z * Hh + blockIdx.y;
    const int tid  = threadIdx.x;
    const int lane = tid & 63;
    const int wv   = tid >> 6;      // 0..7, wave owns q-rows [wv*16, wv*16+16)
    const int c15  = lane & 15;
    const int quad = lane >> 4;

    const float* qptr = q + ((size_t)bh * Tt + blk * 128) * 64;
    const float* kptr = k + ((size_t)bh * Tt + blk * 128) * 64;
    const float* vptr = v + ((size_t)bh * Tt + blk * 128) * 64;
    const float* gkp  = gk + (size_t)bh * Gg * 64;
    const float* gvp  = gv + (size_t)bh * Gg * 64;
    const float* amp  = amask + (size_t)bh * Tt + blk * 128;
    const float* gmp  = gmask + (size_t)bh * Gg;

    // ---- Q as B-operand frags: n=c15 (q-row), k=d=32*half+quad*8+j ----
    bf16x8 qbh[2], qbl[2];
    {
        int row = wv * 16 + c15;
#pragma unroll
        for (int h = 0; h < 2; ++h) {
            f32x4 a = *(const f32x4*)(qptr + row * 64 + h * 32 + quad * 8);
            f32x4 b = *(const f32x4*)(qptr + row * 64 + h * 32 + quad * 8 + 4);
            split8v(a, b, qbh[h], qbl[h]);
        }
    }

    // ---- staging geometry (waves 0-3: K chunk; waves 4-7: V^T chunk) ----
    const int slot = tid & 15;
    const int r0k  = (tid >> 4) & 15;
    const int tV   = tid & 255;
    const int key0 = 4 * (tV & 15);
    const int d0v  = 4 * ((tV >> 4) & 3) + 16 * (tV >> 6);

    int soff[4];
    const float *sloc, *sglb;
    if (wv < 4) {
        sloc = kptr; sglb = gkp;
#pragma unroll
        for (int i = 0; i < 4; ++i) soff[i] = (r0k + i * 16) * 64 + slot * 4;
    } else {
        sloc = vptr; sglb = gvp;
#pragma unroll
        for (int j = 0; j < 4; ++j) soff[j] = (key0 + j) * 64 + d0v;
    }

    f32x4 stg[4];
    auto stage_load = [&](int c) {
        const float* s = (c < 2) ? (sloc + c * 4096) : (sglb + (c - 2) * 4096);
#pragma unroll
        for (int j = 0; j < 4; ++j) stg[j] = *(const f32x4*)(s + soff[j]);
    };
    auto stage_store = [&]() {
        if (wv < 4) {
            unsigned short* kh = (unsigned short*)lds;
            unsigned short* kl = (unsigned short*)(lds + 9216);
#pragma unroll
            for (int i = 0; i < 4; ++i) {
                unsigned int h0, l0, h1, l1;
                split2(stg[i][0], stg[i][1], h0, l0);
                split2(stg[i][2], stg[i][3], h1, l1);
                int o = (r0k + i * 16) * 72 + slot * 4;
                *reinterpret_cast<uint2*>(kh + o) = make_uint2(h0, h1);
                *reinterpret_cast<uint2*>(kl + o) = make_uint2(l0, l1);
            }
        } else {
            unsigned short* vb = (unsigned short*)(lds + 18432);
#pragma unroll
            for (int i = 0; i < 4; ++i) {
                unsigned int h0, l0, h1, l1;
                split2(stg[0][i], stg[1][i], h0, l0);
                split2(stg[2][i], stg[3][i], h1, l1);
                int o = (d0v + i) * 152 + key0 * 2;
                *reinterpret_cast<uint4*>(vb + o) = make_uint4(h0, h1, l0, l1);
            }
        }
    };

    // ---- prologue: fill buffer with chunk 0 ----
    stage_load(0);
    stage_store();
    __syncthreads();

    const f32x4 zero4 = {0.f, 0.f, 0.f, 0.f};
    f32x4 ctx[4];  // ctx^T[d=dm*16+quad*4+r][q=c15]
#pragma unroll
    for (int dm = 0; dm < 4; ++dm) ctx[dm] = zero4;
    float m_run = -3.4e38f;  // running max, log2 units
    float l_run = 0.f;       // per-lane partial; cross-quad reduce in epilogue

    const unsigned short* k_hi = (const unsigned short*)lds;
    const unsigned short* k_lo = (const unsigned short*)(lds + 9216);
    const unsigned int*   v_il = (const unsigned int*)(lds + 18432);

#pragma unroll
    for (int c = 0; c < 4; ++c) {
        // masks for THIS chunk, vectorized; issued before the stage prefetch
        // so their vmcnt wait cannot drain the prefetch behind them.
        const float* mb = (c < 2) ? (amp + c * 64) : (gmp + (c - 2) * 64);
        f32x4 mkl[4];
#pragma unroll
        for (int km = 0; km < 4; ++km) {
            f32x4 m = *(const f32x4*)(mb + km * 16 + quad * 4);
            mkl[km] = m * LOG2E;
        }

        // T14 issue-early: next chunk's global loads in flight during compute
        if (c < 3) stage_load(c + 1);

        // ---- S^T = K·Q^T : D[m=key=km*16+quad*4+r][n=q=c15] ----
        f32x4 S[4];
#pragma unroll
        for (int km = 0; km < 4; ++km) S[km] = zero4;

        __builtin_amdgcn_s_setprio(1);
#pragma unroll
        for (int km = 0; km < 4; ++km) {
            int krow = km * 16 + c15;
            bf16x8 kh0 = *(const bf16x8*)(k_hi + krow * 72 + quad * 8);
            bf16x8 kh1 = *(const bf16x8*)(k_hi + krow * 72 + quad * 8 + 32);
            bf16x8 kl0 = *(const bf16x8*)(k_lo + krow * 72 + quad * 8);
            bf16x8 kl1 = *(const bf16x8*)(k_lo + krow * 72 + quad * 8 + 32);
            f32x4 a = S[km];
            a = MFMA32(kh0, qbh[0], a);
            a = MFMA32(kh1, qbh[1], a);
            a = MFMA32(kh0, qbl[0], a);
            a = MFMA32(kh1, qbl[1], a);
            a = MFMA32(kl0, qbh[0], a);
            a = MFMA32(kl1, qbh[1], a);
            S[km] = a;
        }
        __builtin_amdgcn_s_setprio(0);

        // ---- online softmax, log2 domain, deferred max + deferred sum ----
        bf16x4 ph[4];
        {
            float pmax = -3.4e38f;
#pragma unroll
            for (int km = 0; km < 4; ++km)
#pragma unroll
                for (int r = 0; r < 4; ++r) {
                    float s = fmaf(S[km][r], QSCALE, mkl[km][r]);
                    S[km][r] = s;
                    pmax = fmaxf(pmax, s);
                }
            if (!__all(pmax <= m_run + DEFER_THR)) {
                float mx = fmaxf(pmax, __shfl_xor(pmax, 16));
                mx = fmaxf(mx, __shfl_xor(mx, 32));
                float mn = fmaxf(m_run, mx);
                float alpha = __builtin_amdgcn_exp2f(m_run - mn);
                m_run = mn;
                l_run *= alpha;
#pragma unroll
                for (int dm = 0; dm < 4; ++dm) {
                    ctx[dm][0] *= alpha; ctx[dm][1] *= alpha;
                    ctx[dm][2] *= alpha; ctx[dm][3] *= alpha;
                }
            }
            float sm = 0.f;
#pragma unroll
            for (int km = 0; km < 4; ++km) {
#pragma unroll
                for (int r = 0; r < 4; ++r) {
                    float e = __builtin_amdgcn_exp2f(S[km][r] - m_run);
                    S[km][r] = e;
                    sm += e;
                }
                union { bf16x4 b; uint2 u; } P;
                P.u.x = cvt_pk(S[km][0], S[km][1]);
                P.u.y = cvt_pk(S[km][2], S[km][3]);
                ph[km] = P.b;
            }
            l_run += sm;
        }

        // ---- ctx^T += (V^T_hi + V^T_lo) · P^T (mfma 16x16x16) ----
        __builtin_amdgcn_s_setprio(1);
#pragma unroll
        for (int dm = 0; dm < 4; ++dm) {
            int drow = dm * 16 + c15;
            f32x4 a = ctx[dm];
#pragma unroll
            for (int km = 0; km < 4; ++km) {
                uint4 w = *(const uint4*)(v_il + drow * 76 + (km * 4 + quad) * 4);
                union { uint2 u; bf16x4 b; } vh, vl;
                vh.u = make_uint2(w.x, w.y);
                vl.u = make_uint2(w.z, w.w);
                a = MFMA16(vh.b, ph[km], a);
                a = MFMA16(vl.b, ph[km], a);
            }
            ctx[dm] = a;
        }
        __builtin_amdgcn_s_setprio(0);

        // T14 write-late: all reads of chunk c done -> overwrite buffer
        if (c < 3) {
            __syncthreads();
            stage_store();
            __syncthreads();
        }
    }

    // ---- epilogue: reduce l across quads, normalize, bounce through LDS ----
    __syncthreads();  // all waves' chunk-3 LDS reads done before o_scr reuse
    {
        float l = l_run;
        l += __shfl_xor(l, 16);
        l += __shfl_xor(l, 32);
        float inv = 1.0f / l;
        int row = wv * 16 + c15;
#pragma unroll
        for (int dm = 0; dm < 4; ++dm) {
            f32x4 o = ctx[dm];
            o[0] *= inv; o[1] *= inv; o[2] *= inv; o[3] *= inv;
            *(f32x4*)(o_scr + row * 68 + dm * 16 + quad * 4) = o;
        }
    }
    __syncthreads();
    {
        float* op = out + ((size_t)bh * Tt + blk * 128) * 64;
        const int oslot = tid & 15, or0 = tid >> 4;
#pragma unroll
        for (int i = 0; i < 4; ++i) {
            int row = or0 + i * 32;
            f32x4 val = *(const f32x4*)(o_scr + row * 68 + oslot * 4);
            *(f32x4*)(op + row * 64 + oslot * 4) = val;
        }
    }
}

extern "C" void kernel_launch(void* const* d_in, const int* in_sizes, int n_in,
                              void* d_out, int out_size, void* d_ws, size_t ws_size,
                              hipStream_t stream) {
    (void)in_sizes; (void)n_in; (void)d_ws; (void)ws_size; (void)out_size;
    const float* q  = (const float*)d_in[0];
    const float* k  = (const float*)d_in[1];
    const float* v  = (const float*)d_in[2];
    const float* am = (const float*)d_in[3];
    const float* gk = (const float*)d_in[4];
    const float* gv = (const float*)d_in[5];
    const float* gm = (const float*)d_in[6];
    dim3 grid(32, 16, 4);
    block_attn_kernel<<<grid, dim3(512), 0, stream>>>(q, k, v, am, gk, gv, gm, (float*)d_out);
}

// Round 5
// 264.950 us; speedup vs baseline: 1.2838x; 1.2838x over previous
//
#include <hip/hip_runtime.h>
#include <hip/hip_bf16.h>

// Flash-style block attention, MI355X gfx950. Round 9.
// R8 post-mortem: (512,6) raised occupancy to 3 WG/CU (60%) but the ~110
// live regs spilled at the 84-reg cap (FETCH 115->329MB, WRITE 65->398MB =
// scratch). R9 keeps the occupancy win and cuts ~32 regs of live state:
//  - NO register prefetch (stg gone, -16): staging loads issue between the
//    two chunk barriers; latency is covered by 24 waves/CU TLP (that's what
//    occupancy is FOR). This is why R5 showed dbuf/prefetch hides nothing.
//  - masks in LDS (-16 live range): mask depends only on key index; all 8
//    waves were loading the SAME 64 floats into regs. Wave 0 stages
//    m*log2e into 256B LDS; softmax reads 4x broadcast ds_read_b128 at use.
//  - All R6 wins kept: P single-bf16, exp2 domain, defer-max, deferred
//    l-sum, V hi/lo interleaved (b128), setprio. Single 37888B buffer.
// Predicted: no scratch (WRITE=65536KB), dur ~78-85us/dispatch, Occ ~60%,
// MfmaUtil ~31%, VALUBusy ~45%.

typedef __attribute__((ext_vector_type(8))) short bf16x8;
typedef __attribute__((ext_vector_type(4))) short bf16x4;
typedef __attribute__((ext_vector_type(4))) float f32x4;

#define MFMA32(A, B, C) __builtin_amdgcn_mfma_f32_16x16x32_bf16((A), (B), (C), 0, 0, 0)
#define MFMA16(A, B, C) __builtin_amdgcn_mfma_f32_16x16x16bf16_1k((A), (B), (C), 0, 0, 0)

__device__ __forceinline__ unsigned int cvt_pk(float a, float b) {
    __hip_bfloat162 h = __float22bfloat162_rn(float2{a, b});
    union { __hip_bfloat162 h; unsigned int u; } c;
    c.h = h;
    return c.u;
}
__device__ __forceinline__ void split2(float a, float b, unsigned int& hi, unsigned int& lo) {
    unsigned int h = cvt_pk(a, b);
    float ra = a - __uint_as_float(h << 16);
    float rb = b - __uint_as_float(h & 0xFFFF0000u);
    hi = h;
    lo = cvt_pk(ra, rb);
}
__device__ __forceinline__ void split8v(f32x4 a, f32x4 b, bf16x8& hi, bf16x8& lo) {
    union { bf16x8 v; unsigned int w[4]; } H, L;
    split2(a[0], a[1], H.w[0], L.w[0]);
    split2(a[2], a[3], H.w[1], L.w[1]);
    split2(b[0], b[1], H.w[2], L.w[2]);
    split2(b[2], b[3], H.w[3], L.w[3]);
    hi = H.v; lo = L.v;
}

// LDS: K_hi [64][72] (9216) | K_lo [64][72] (9216) | V^T interleaved
// [64][152 hw] (19456) | mask [64] f32 (256). Total 38144 B.
// Epilogue reuses bytes [0,34816) as [128][68] f32.
#define BUF_BYTES 37888
#define LDS_BYTES 38144

#define LOG2E 1.44269504f
#define QSCALE 0.180336880f  /* 0.125 * log2(e) */
#define DEFER_THR 8.0f

__global__ __launch_bounds__(512, 6) void block_attn_kernel(
    const float* __restrict__ q, const float* __restrict__ k,
    const float* __restrict__ v, const float* __restrict__ amask,
    const float* __restrict__ gk, const float* __restrict__ gv,
    const float* __restrict__ gmask, float* __restrict__ out) {
    constexpr int Hh = 16, Tt = 4096, Gg = 128;

    __shared__ __align__(16) unsigned char lds[LDS_BYTES];
    float* o_scr = (float*)lds;                  // [128][68] epilogue scratch
    float* m_lds = (float*)(lds + BUF_BYTES);    // [64] mask * log2e

    const int blk = blockIdx.x;
    const int bh  = blockIdx.z * Hh + blockIdx.y;
    const int tid  = threadIdx.x;
    const int lane = tid & 63;
    const int wv   = tid >> 6;      // 0..7, wave owns q-rows [wv*16, wv*16+16)
    const int c15  = lane & 15;
    const int quad = lane >> 4;

    const float* qptr = q + ((size_t)bh * Tt + blk * 128) * 64;
    const float* kptr = k + ((size_t)bh * Tt + blk * 128) * 64;
    const float* vptr = v + ((size_t)bh * Tt + blk * 128) * 64;
    const float* gkp  = gk + (size_t)bh * Gg * 64;
    const float* gvp  = gv + (size_t)bh * Gg * 64;
    const float* amp  = amask + (size_t)bh * Tt + blk * 128;
    const float* gmp  = gmask + (size_t)bh * Gg;

    // ---- Q as B-operand frags: n=c15 (q-row), k=d=32*half+quad*8+j ----
    bf16x8 qbh[2], qbl[2];
    {
        int row = wv * 16 + c15;
#pragma unroll
        for (int h = 0; h < 2; ++h) {
            f32x4 a = *(const f32x4*)(qptr + row * 64 + h * 32 + quad * 8);
            f32x4 b = *(const f32x4*)(qptr + row * 64 + h * 32 + quad * 8 + 4);
            split8v(a, b, qbh[h], qbl[h]);
        }
    }

    // ---- staging geometry (waves 0-3: K chunk; waves 4-7: V^T chunk) ----
    const int slot = tid & 15;
    const int r0k  = (tid >> 4) & 15;
    const int tV   = tid & 255;
    const int key0 = 4 * (tV & 15);
    const int d0v  = 4 * ((tV >> 4) & 3) + 16 * (tV >> 6);

    // load + convert + LDS-store for chunk c (no reg prefetch: TLP covers it)
    auto stage = [&](int c) {
        if (wv < 4) {
            const float* s = (c < 2) ? (kptr + c * 4096) : (gkp + (c - 2) * 4096);
            unsigned short* kh = (unsigned short*)lds;
            unsigned short* kl = (unsigned short*)(lds + 9216);
            f32x4 t[4];
#pragma unroll
            for (int i = 0; i < 4; ++i)
                t[i] = *(const f32x4*)(s + (r0k + i * 16) * 64 + slot * 4);
#pragma unroll
            for (int i = 0; i < 4; ++i) {
                unsigned int h0, l0, h1, l1;
                split2(t[i][0], t[i][1], h0, l0);
                split2(t[i][2], t[i][3], h1, l1);
                int o = (r0k + i * 16) * 72 + slot * 4;
                *reinterpret_cast<uint2*>(kh + o) = make_uint2(h0, h1);
                *reinterpret_cast<uint2*>(kl + o) = make_uint2(l0, l1);
            }
        } else {
            const float* s = (c < 2) ? (vptr + c * 4096) : (gvp + (c - 2) * 4096);
            unsigned short* vb = (unsigned short*)(lds + 18432);
            f32x4 t[4];
#pragma unroll
            for (int j = 0; j < 4; ++j)
                t[j] = *(const f32x4*)(s + (key0 + j) * 64 + d0v);
#pragma unroll
            for (int i = 0; i < 4; ++i) {
                unsigned int h0, l0, h1, l1;
                split2(t[0][i], t[1][i], h0, l0);
                split2(t[2][i], t[3][i], h1, l1);
                int o = (d0v + i) * 152 + key0 * 2;
                *reinterpret_cast<uint4*>(vb + o) = make_uint4(h0, h1, l0, l1);
            }
        }
        if (tid < 64) {
            float m = (c < 2) ? amp[c * 64 + tid] : gmp[(c - 2) * 64 + tid];
            m_lds[tid] = m * LOG2E;
        }
    };

    // ---- prologue: fill buffer with chunk 0 ----
    stage(0);
    __syncthreads();

    const f32x4 zero4 = {0.f, 0.f, 0.f, 0.f};
    f32x4 ctx[4];  // ctx^T[d=dm*16+quad*4+r][q=c15]
#pragma unroll
    for (int dm = 0; dm < 4; ++dm) ctx[dm] = zero4;
    float m_run = -3.4e38f;  // running max, log2 units
    float l_run = 0.f;       // per-lane partial; cross-quad reduce in epilogue

    const unsigned short* k_hi = (const unsigned short*)lds;
    const unsigned short* k_lo = (const unsigned short*)(lds + 9216);
    const unsigned int*   v_il = (const unsigned int*)(lds + 18432);

#pragma unroll
    for (int c = 0; c < 4; ++c) {
        // ---- S^T = K·Q^T : D[m=key=km*16+quad*4+r][n=q=c15] ----
        f32x4 S[4];
#pragma unroll
        for (int km = 0; km < 4; ++km) S[km] = zero4;

        __builtin_amdgcn_s_setprio(1);
#pragma unroll
        for (int km = 0; km < 4; ++km) {
            int krow = km * 16 + c15;
            bf16x8 kh0 = *(const bf16x8*)(k_hi + krow * 72 + quad * 8);
            bf16x8 kh1 = *(const bf16x8*)(k_hi + krow * 72 + quad * 8 + 32);
            bf16x8 kl0 = *(const bf16x8*)(k_lo + krow * 72 + quad * 8);
            bf16x8 kl1 = *(const bf16x8*)(k_lo + krow * 72 + quad * 8 + 32);
            f32x4 a = S[km];
            a = MFMA32(kh0, qbh[0], a);
            a = MFMA32(kh1, qbh[1], a);
            a = MFMA32(kh0, qbl[0], a);
            a = MFMA32(kh1, qbl[1], a);
            a = MFMA32(kl0, qbh[0], a);
            a = MFMA32(kl1, qbh[1], a);
            S[km] = a;
        }
        __builtin_amdgcn_s_setprio(0);

        // ---- online softmax, log2 domain, deferred max + deferred sum ----
        bf16x4 ph[4];
        {
            // masks from LDS (broadcast reads; live only inside softmax)
            f32x4 mkl[4];
#pragma unroll
            for (int km = 0; km < 4; ++km)
                mkl[km] = *(const f32x4*)(m_lds + km * 16 + quad * 4);

            float pmax = -3.4e38f;
#pragma unroll
            for (int km = 0; km < 4; ++km)
#pragma unroll
                for (int r = 0; r < 4; ++r) {
                    float s = fmaf(S[km][r], QSCALE, mkl[km][r]);
                    S[km][r] = s;
                    pmax = fmaxf(pmax, s);
                }
            if (!__all(pmax <= m_run + DEFER_THR)) {
                float mx = fmaxf(pmax, __shfl_xor(pmax, 16));
                mx = fmaxf(mx, __shfl_xor(mx, 32));
                float mn = fmaxf(m_run, mx);
                float alpha = __builtin_amdgcn_exp2f(m_run - mn);
                m_run = mn;
                l_run *= alpha;
#pragma unroll
                for (int dm = 0; dm < 4; ++dm) {
                    ctx[dm][0] *= alpha; ctx[dm][1] *= alpha;
                    ctx[dm][2] *= alpha; ctx[dm][3] *= alpha;
                }
            }
            float sm = 0.f;
#pragma unroll
            for (int km = 0; km < 4; ++km) {
#pragma unroll
                for (int r = 0; r < 4; ++r) {
                    float e = __builtin_amdgcn_exp2f(S[km][r] - m_run);
                    S[km][r] = e;
                    sm += e;
                }
                union { bf16x4 b; uint2 u; } P;
                P.u.x = cvt_pk(S[km][0], S[km][1]);
                P.u.y = cvt_pk(S[km][2], S[km][3]);
                ph[km] = P.b;
            }
            l_run += sm;
        }

        // ---- ctx^T += (V^T_hi + V^T_lo) · P^T (mfma 16x16x16) ----
        __builtin_amdgcn_s_setprio(1);
#pragma unroll
        for (int dm = 0; dm < 4; ++dm) {
            int drow = dm * 16 + c15;
            f32x4 a = ctx[dm];
#pragma unroll
            for (int km = 0; km < 4; ++km) {
                uint4 w = *(const uint4*)(v_il + drow * 76 + (km * 4 + quad) * 4);
                union { uint2 u; bf16x4 b; } vh, vl;
                vh.u = make_uint2(w.x, w.y);
                vl.u = make_uint2(w.z, w.w);
                a = MFMA16(vh.b, ph[km], a);
                a = MFMA16(vl.b, ph[km], a);
            }
            ctx[dm] = a;
        }
        __builtin_amdgcn_s_setprio(0);

        // stage next chunk; latency exposed here but covered by 3 WGs/CU TLP
        if (c < 3) {
            __syncthreads();
            stage(c + 1);
            __syncthreads();
        }
    }

    // ---- epilogue: reduce l across quads, normalize, bounce through LDS ----
    __syncthreads();  // all waves' chunk-3 LDS reads done before o_scr reuse
    {
        float l = l_run;
        l += __shfl_xor(l, 16);
        l += __shfl_xor(l, 32);
        float inv = 1.0f / l;
        int row = wv * 16 + c15;
#pragma unroll
        for (int dm = 0; dm < 4; ++dm) {
            f32x4 o = ctx[dm];
            o[0] *= inv; o[1] *= inv; o[2] *= inv; o[3] *= inv;
            *(f32x4*)(o_scr + row * 68 + dm * 16 + quad * 4) = o;
        }
    }
    __syncthreads();
    {
        float* op = out + ((size_t)bh * Tt + blk * 128) * 64;
        const int oslot = tid & 15, or0 = tid >> 4;
#pragma unroll
        for (int i = 0; i < 4; ++i) {
            int row = or0 + i * 32;
            f32x4 val = *(const f32x4*)(o_scr + row * 68 + oslot * 4);
            *(f32x4*)(op + row * 64 + oslot * 4) = val;
        }
    }
}

extern "C" void kernel_launch(void* const* d_in, const int* in_sizes, int n_in,
                              void* d_out, int out_size, void* d_ws, size_t ws_size,
                              hipStream_t stream) {
    (void)in_sizes; (void)n_in; (void)d_ws; (void)ws_size; (void)out_size;
    const float* q  = (const float*)d_in[0];
    const float* k  = (const float*)d_in[1];
    const float* v  = (const float*)d_in[2];
    const float* am = (const float*)d_in[3];
    const float* gk = (const float*)d_in[4];
    const float* gv = (const float*)d_in[5];
    const float* gm = (const float*)d_in[6];
    dim3 grid(32, 16, 4);
    block_attn_kernel<<<grid, dim3(512), 0, stream>>>(q, k, v, am, gk, gv, gm, (float*)d_out);
}

// Round 6
// 261.849 us; speedup vs baseline: 1.2990x; 1.0118x over previous
//
#include <hip/hip_runtime.h>
#include <hip/hip_bf16.h>

// Flash-style block attention, MI355X gfx950. Round 10.
// R9 post-mortem: 3 WGs/CU achieved (58% occ) but STILL spilling at the
// 84-reg cap (WRITE 65->168MB scratch). Phase peaks were: softmax 82
// (mkl[4]=16 live), QK 74+hoisting (K frags 16 transient). R10 shaves both:
//  - Two-pass QK: pass A = kh0/kh1 (8 transient) x4 hi-MFMAs; pass B =
//    kl0/kl1 (8 transient) x2 lo-MFMAs into same S. Same MFMA count, same
//    LDS traffic (each frag read once). QK peak 74 -> 66.
//  - mkl per-km inside softmax (4-reg transient, not 16 live): peak 82->70.
//  - Stage t[4] kept (stage phase is the LOW-pressure phase, ~58 live).
//  - All else from R9: single 37888B buffer + mask in LDS, (512,6),
//    P single-bf16, exp2 domain, defer-max, deferred l-sum, interleaved V.
// Predicted: no scratch (WRITE=65536KB, FETCH~115.5MB), dur ~78-85us,
// MfmaUtil ~31%, VALUBusy ~45%, Occ ~58%.

typedef __attribute__((ext_vector_type(8))) short bf16x8;
typedef __attribute__((ext_vector_type(4))) short bf16x4;
typedef __attribute__((ext_vector_type(4))) float f32x4;

#define MFMA32(A, B, C) __builtin_amdgcn_mfma_f32_16x16x32_bf16((A), (B), (C), 0, 0, 0)
#define MFMA16(A, B, C) __builtin_amdgcn_mfma_f32_16x16x16bf16_1k((A), (B), (C), 0, 0, 0)

__device__ __forceinline__ unsigned int cvt_pk(float a, float b) {
    __hip_bfloat162 h = __float22bfloat162_rn(float2{a, b});
    union { __hip_bfloat162 h; unsigned int u; } c;
    c.h = h;
    return c.u;
}
__device__ __forceinline__ void split2(float a, float b, unsigned int& hi, unsigned int& lo) {
    unsigned int h = cvt_pk(a, b);
    float ra = a - __uint_as_float(h << 16);
    float rb = b - __uint_as_float(h & 0xFFFF0000u);
    hi = h;
    lo = cvt_pk(ra, rb);
}
__device__ __forceinline__ void split8v(f32x4 a, f32x4 b, bf16x8& hi, bf16x8& lo) {
    union { bf16x8 v; unsigned int w[4]; } H, L;
    split2(a[0], a[1], H.w[0], L.w[0]);
    split2(a[2], a[3], H.w[1], L.w[1]);
    split2(b[0], b[1], H.w[2], L.w[2]);
    split2(b[2], b[3], H.w[3], L.w[3]);
    hi = H.v; lo = L.v;
}

// LDS: K_hi [64][72] (9216) | K_lo [64][72] (9216) | V^T interleaved
// [64][152 hw] (19456) | mask [64] f32 (256). Total 38144 B.
// Epilogue reuses bytes [0,34816) as [128][68] f32.
#define BUF_BYTES 37888
#define LDS_BYTES 38144

#define LOG2E 1.44269504f
#define QSCALE 0.180336880f  /* 0.125 * log2(e) */
#define DEFER_THR 8.0f

__global__ __launch_bounds__(512, 6) void block_attn_kernel(
    const float* __restrict__ q, const float* __restrict__ k,
    const float* __restrict__ v, const float* __restrict__ amask,
    const float* __restrict__ gk, const float* __restrict__ gv,
    const float* __restrict__ gmask, float* __restrict__ out) {
    constexpr int Hh = 16, Tt = 4096, Gg = 128;

    __shared__ __align__(16) unsigned char lds[LDS_BYTES];
    float* o_scr = (float*)lds;                  // [128][68] epilogue scratch
    float* m_lds = (float*)(lds + BUF_BYTES);    // [64] mask * log2e

    const int blk = blockIdx.x;
    const int bh  = blockIdx.z * Hh + blockIdx.y;
    const int tid  = threadIdx.x;
    const int lane = tid & 63;
    const int wv   = tid >> 6;      // 0..7, wave owns q-rows [wv*16, wv*16+16)
    const int c15  = lane & 15;
    const int quad = lane >> 4;

    const float* qptr = q + ((size_t)bh * Tt + blk * 128) * 64;
    const float* kptr = k + ((size_t)bh * Tt + blk * 128) * 64;
    const float* vptr = v + ((size_t)bh * Tt + blk * 128) * 64;
    const float* gkp  = gk + (size_t)bh * Gg * 64;
    const float* gvp  = gv + (size_t)bh * Gg * 64;
    const float* amp  = amask + (size_t)bh * Tt + blk * 128;
    const float* gmp  = gmask + (size_t)bh * Gg;

    // ---- Q as B-operand frags: n=c15 (q-row), k=d=32*half+quad*8+j ----
    bf16x8 qbh[2], qbl[2];
    {
        int row = wv * 16 + c15;
#pragma unroll
        for (int h = 0; h < 2; ++h) {
            f32x4 a = *(const f32x4*)(qptr + row * 64 + h * 32 + quad * 8);
            f32x4 b = *(const f32x4*)(qptr + row * 64 + h * 32 + quad * 8 + 4);
            split8v(a, b, qbh[h], qbl[h]);
        }
    }

    // ---- staging geometry (waves 0-3: K chunk; waves 4-7: V^T chunk) ----
    const int slot = tid & 15;
    const int r0k  = (tid >> 4) & 15;
    const int tV   = tid & 255;
    const int key0 = 4 * (tV & 15);
    const int d0v  = 4 * ((tV >> 4) & 3) + 16 * (tV >> 6);

    // load + convert + LDS-store for chunk c (no reg prefetch: TLP covers it)
    auto stage = [&](int c) {
        if (wv < 4) {
            const float* s = (c < 2) ? (kptr + c * 4096) : (gkp + (c - 2) * 4096);
            unsigned short* kh = (unsigned short*)lds;
            unsigned short* kl = (unsigned short*)(lds + 9216);
            f32x4 t[4];
#pragma unroll
            for (int i = 0; i < 4; ++i)
                t[i] = *(const f32x4*)(s + (r0k + i * 16) * 64 + slot * 4);
#pragma unroll
            for (int i = 0; i < 4; ++i) {
                unsigned int h0, l0, h1, l1;
                split2(t[i][0], t[i][1], h0, l0);
                split2(t[i][2], t[i][3], h1, l1);
                int o = (r0k + i * 16) * 72 + slot * 4;
                *reinterpret_cast<uint2*>(kh + o) = make_uint2(h0, h1);
                *reinterpret_cast<uint2*>(kl + o) = make_uint2(l0, l1);
            }
        } else {
            const float* s = (c < 2) ? (vptr + c * 4096) : (gvp + (c - 2) * 4096);
            unsigned short* vb = (unsigned short*)(lds + 18432);
            f32x4 t[4];
#pragma unroll
            for (int j = 0; j < 4; ++j)
                t[j] = *(const f32x4*)(s + (key0 + j) * 64 + d0v);
#pragma unroll
            for (int i = 0; i < 4; ++i) {
                unsigned int h0, l0, h1, l1;
                split2(t[0][i], t[1][i], h0, l0);
                split2(t[2][i], t[3][i], h1, l1);
                int o = (d0v + i) * 152 + key0 * 2;
                *reinterpret_cast<uint4*>(vb + o) = make_uint4(h0, h1, l0, l1);
            }
        }
        if (tid < 64) {
            float m = (c < 2) ? amp[c * 64 + tid] : gmp[(c - 2) * 64 + tid];
            m_lds[tid] = m * LOG2E;
        }
    };

    // ---- prologue: fill buffer with chunk 0 ----
    stage(0);
    __syncthreads();

    const f32x4 zero4 = {0.f, 0.f, 0.f, 0.f};
    f32x4 ctx[4];  // ctx^T[d=dm*16+quad*4+r][q=c15]
#pragma unroll
    for (int dm = 0; dm < 4; ++dm) ctx[dm] = zero4;
    float m_run = -3.4e38f;  // running max, log2 units
    float l_run = 0.f;       // per-lane partial; cross-quad reduce in epilogue

    const unsigned short* k_hi = (const unsigned short*)lds;
    const unsigned short* k_lo = (const unsigned short*)(lds + 9216);
    const unsigned int*   v_il = (const unsigned int*)(lds + 18432);

#pragma unroll
    for (int c = 0; c < 4; ++c) {
        // ---- S^T = K·Q^T : D[m=key=km*16+quad*4+r][n=q=c15] ----
        // Two passes over LDS to cap K-fragment transient pressure at 8 regs.
        f32x4 S[4];
#pragma unroll
        for (int km = 0; km < 4; ++km) S[km] = zero4;

        __builtin_amdgcn_s_setprio(1);
#pragma unroll
        for (int km = 0; km < 4; ++km) {  // pass A: K_hi x (Q_hi, Q_lo)
            int krow = km * 16 + c15;
            bf16x8 kh0 = *(const bf16x8*)(k_hi + krow * 72 + quad * 8);
            bf16x8 kh1 = *(const bf16x8*)(k_hi + krow * 72 + quad * 8 + 32);
            f32x4 a = S[km];
            a = MFMA32(kh0, qbh[0], a);
            a = MFMA32(kh1, qbh[1], a);
            a = MFMA32(kh0, qbl[0], a);
            a = MFMA32(kh1, qbl[1], a);
            S[km] = a;
        }
#pragma unroll
        for (int km = 0; km < 4; ++km) {  // pass B: K_lo x Q_hi
            int krow = km * 16 + c15;
            bf16x8 kl0 = *(const bf16x8*)(k_lo + krow * 72 + quad * 8);
            bf16x8 kl1 = *(const bf16x8*)(k_lo + krow * 72 + quad * 8 + 32);
            f32x4 a = S[km];
            a = MFMA32(kl0, qbh[0], a);
            a = MFMA32(kl1, qbh[1], a);
            S[km] = a;
        }
        __builtin_amdgcn_s_setprio(0);

        // ---- online softmax, log2 domain, deferred max + deferred sum ----
        bf16x4 ph[4];
        {
            float pmax = -3.4e38f;
#pragma unroll
            for (int km = 0; km < 4; ++km) {
                // mask from LDS per-km: 4-reg transient, not 16 live
                f32x4 mkl = *(const f32x4*)(m_lds + km * 16 + quad * 4);
#pragma unroll
                for (int r = 0; r < 4; ++r) {
                    float s = fmaf(S[km][r], QSCALE, mkl[r]);
                    S[km][r] = s;
                    pmax = fmaxf(pmax, s);
                }
            }
            if (!__all(pmax <= m_run + DEFER_THR)) {
                float mx = fmaxf(pmax, __shfl_xor(pmax, 16));
                mx = fmaxf(mx, __shfl_xor(mx, 32));
                float mn = fmaxf(m_run, mx);
                float alpha = __builtin_amdgcn_exp2f(m_run - mn);
                m_run = mn;
                l_run *= alpha;
#pragma unroll
                for (int dm = 0; dm < 4; ++dm) {
                    ctx[dm][0] *= alpha; ctx[dm][1] *= alpha;
                    ctx[dm][2] *= alpha; ctx[dm][3] *= alpha;
                }
            }
            float sm = 0.f;
#pragma unroll
            for (int km = 0; km < 4; ++km) {
#pragma unroll
                for (int r = 0; r < 4; ++r) {
                    float e = __builtin_amdgcn_exp2f(S[km][r] - m_run);
                    S[km][r] = e;
                    sm += e;
                }
                union { bf16x4 b; uint2 u; } P;
                P.u.x = cvt_pk(S[km][0], S[km][1]);
                P.u.y = cvt_pk(S[km][2], S[km][3]);
                ph[km] = P.b;
            }
            l_run += sm;
        }

        // ---- ctx^T += (V^T_hi + V^T_lo) · P^T (mfma 16x16x16) ----
        __builtin_amdgcn_s_setprio(1);
#pragma unroll
        for (int dm = 0; dm < 4; ++dm) {
            int drow = dm * 16 + c15;
            f32x4 a = ctx[dm];
#pragma unroll
            for (int km = 0; km < 4; ++km) {
                uint4 w = *(const uint4*)(v_il + drow * 76 + (km * 4 + quad) * 4);
                union { uint2 u; bf16x4 b; } vh, vl;
                vh.u = make_uint2(w.x, w.y);
                vl.u = make_uint2(w.z, w.w);
                a = MFMA16(vh.b, ph[km], a);
                a = MFMA16(vl.b, ph[km], a);
            }
            ctx[dm] = a;
        }
        __builtin_amdgcn_s_setprio(0);

        // stage next chunk; latency exposed here but covered by 3 WGs/CU TLP
        if (c < 3) {
            __syncthreads();
            stage(c + 1);
            __syncthreads();
        }
    }

    // ---- epilogue: reduce l across quads, normalize, bounce through LDS ----
    __syncthreads();  // all waves' chunk-3 LDS reads done before o_scr reuse
    {
        float l = l_run;
        l += __shfl_xor(l, 16);
        l += __shfl_xor(l, 32);
        float inv = 1.0f / l;
        int row = wv * 16 + c15;
#pragma unroll
        for (int dm = 0; dm < 4; ++dm) {
            f32x4 o = ctx[dm];
            o[0] *= inv; o[1] *= inv; o[2] *= inv; o[3] *= inv;
            *(f32x4*)(o_scr + row * 68 + dm * 16 + quad * 4) = o;
        }
    }
    __syncthreads();
    {
        float* op = out + ((size_t)bh * Tt + blk * 128) * 64;
        const int oslot = tid & 15, or0 = tid >> 4;
#pragma unroll
        for (int i = 0; i < 4; ++i) {
            int row = or0 + i * 32;
            f32x4 val = *(const f32x4*)(o_scr + row * 68 + oslot * 4);
            *(f32x4*)(op + row * 64 + oslot * 4) = val;
        }
    }
}

extern "C" void kernel_launch(void* const* d_in, const int* in_sizes, int n_in,
                              void* d_out, int out_size, void* d_ws, size_t ws_size,
                              hipStream_t stream) {
    (void)in_sizes; (void)n_in; (void)d_ws; (void)ws_size; (void)out_size;
    const float* q  = (const float*)d_in[0];
    const float* k  = (const float*)d_in[1];
    const float* v  = (const float*)d_in[2];
    const float* am = (const float*)d_in[3];
    const float* gk = (const float*)d_in[4];
    const float* gv = (const float*)d_in[5];
    const float* gm = (const float*)d_in[6];
    dim3 grid(32, 16, 4);
    block_attn_kernel<<<grid, dim3(512), 0, stream>>>(q, k, v, am, gk, gv, gm, (float*)d_out);
}

// Round 7
// 250.901 us; speedup vs baseline: 1.3557x; 1.0436x over previous
//
#include <hip/hip_runtime.h>
#include <hip/hip_bf16.h>

// Flash-style block attention, MI355X gfx950. Round 11.
// R8-R10 verdict: 3 WGs/CU (85-reg cap) unreachable without spills; 512-thread
// WGs quantize occupancy to 16 or 24 waves, nothing between. Back to 2 WGs/CU
// (128-reg cap) and spend the register headroom on T15 (R7's idea), which
// failed there ONLY by spilling (+12MB scratch). R11 = T15 + R10's reg diet:
//  - Sb[2][4]: QK(c+1) [MFMA] runs before softmax(c) [VALU] + PV(c); the
//    scheduler interleaves them -> softmax hidden in 3 of 4 chunks.
//  - Diet vs R7: no stg[] reg prefetch (-16; worth ~3us at 2WG per R4/R5),
//    masks in LDS per buffer (-16 live), two-pass QK (-8 transient).
//  - Double-buffered LDS slots (2 x 38144 B = 76.3 KB), 2 WGs/CU, one
//    bar;stage;bar pair per staged chunk (iters 0,1 only).
//  - Budget: 48 AGPR (ctx+Sb) + ~55 arch VGPR ~= 103 < 128 -> no spill.
// Predicted: WRITE=65536KB FETCH~115.5MB (spill gone = primary signal),
// dur ~88us/dispatch, VGPR ~56-64, Occ ~40%, MfmaUtil ~28%, VALU ~40%.

typedef __attribute__((ext_vector_type(8))) short bf16x8;
typedef __attribute__((ext_vector_type(4))) short bf16x4;
typedef __attribute__((ext_vector_type(4))) float f32x4;

#define MFMA32(A, B, C) __builtin_amdgcn_mfma_f32_16x16x32_bf16((A), (B), (C), 0, 0, 0)
#define MFMA16(A, B, C) __builtin_amdgcn_mfma_f32_16x16x16bf16_1k((A), (B), (C), 0, 0, 0)

__device__ __forceinline__ unsigned int cvt_pk(float a, float b) {
    __hip_bfloat162 h = __float22bfloat162_rn(float2{a, b});
    union { __hip_bfloat162 h; unsigned int u; } c;
    c.h = h;
    return c.u;
}
__device__ __forceinline__ void split2(float a, float b, unsigned int& hi, unsigned int& lo) {
    unsigned int h = cvt_pk(a, b);
    float ra = a - __uint_as_float(h << 16);
    float rb = b - __uint_as_float(h & 0xFFFF0000u);
    hi = h;
    lo = cvt_pk(ra, rb);
}
__device__ __forceinline__ void split8v(f32x4 a, f32x4 b, bf16x8& hi, bf16x8& lo) {
    union { bf16x8 v; unsigned int w[4]; } H, L;
    split2(a[0], a[1], H.w[0], L.w[0]);
    split2(a[2], a[3], H.w[1], L.w[1]);
    split2(b[0], b[1], H.w[2], L.w[2]);
    split2(b[2], b[3], H.w[3], L.w[3]);
    hi = H.v; lo = L.v;
}

// Per-slot layout: K_hi [64][72] (9216) | K_lo [64][72] (9216) | V^T
// interleaved [64][152 hw] (19456) | mask*log2e [64] f32 (256) = 38144 B.
// Two slots = 76288 B. Epilogue reuses bytes [0,34816) as [128][68] f32.
#define SLOT_BYTES 38144

#define LOG2E 1.44269504f
#define QSCALE 0.180336880f  /* 0.125 * log2(e) */
#define DEFER_THR 8.0f

__global__ __launch_bounds__(512, 4) void block_attn_kernel(
    const float* __restrict__ q, const float* __restrict__ k,
    const float* __restrict__ v, const float* __restrict__ amask,
    const float* __restrict__ gk, const float* __restrict__ gv,
    const float* __restrict__ gmask, float* __restrict__ out) {
    constexpr int Hh = 16, Tt = 4096, Gg = 128;

    __shared__ __align__(16) unsigned char lds[2 * SLOT_BYTES];
    float* o_scr = (float*)lds;  // [128][68] epilogue scratch (slot 0 region)

    const int blk = blockIdx.x;
    const int bh  = blockIdx.z * Hh + blockIdx.y;
    const int tid  = threadIdx.x;
    const int lane = tid & 63;
    const int wv   = tid >> 6;      // 0..7, wave owns q-rows [wv*16, wv*16+16)
    const int c15  = lane & 15;
    const int quad = lane >> 4;

    const float* qptr = q + ((size_t)bh * Tt + blk * 128) * 64;
    const float* kptr = k + ((size_t)bh * Tt + blk * 128) * 64;
    const float* vptr = v + ((size_t)bh * Tt + blk * 128) * 64;
    const float* gkp  = gk + (size_t)bh * Gg * 64;
    const float* gvp  = gv + (size_t)bh * Gg * 64;
    const float* amp  = amask + (size_t)bh * Tt + blk * 128;
    const float* gmp  = gmask + (size_t)bh * Gg;

    // ---- Q as B-operand frags: n=c15 (q-row), k=d=32*half+quad*8+j ----
    bf16x8 qbh[2], qbl[2];
    {
        int row = wv * 16 + c15;
#pragma unroll
        for (int h = 0; h < 2; ++h) {
            f32x4 a = *(const f32x4*)(qptr + row * 64 + h * 32 + quad * 8);
            f32x4 b = *(const f32x4*)(qptr + row * 64 + h * 32 + quad * 8 + 4);
            split8v(a, b, qbh[h], qbl[h]);
        }
    }

    // ---- staging geometry (waves 0-3: K chunk; waves 4-7: V^T chunk) ----
    const int slot = tid & 15;
    const int r0k  = (tid >> 4) & 15;
    const int tV   = tid & 255;
    const int key0 = 4 * (tV & 15);
    const int d0v  = 4 * ((tV >> 4) & 3) + 16 * (tV >> 6);

    // load + convert + LDS-store chunk c into slot (c&1). No reg prefetch.
    auto stage = [&](int c) {
        unsigned char* base = lds + (c & 1) * SLOT_BYTES;
        if (wv < 4) {
            const float* s = (c < 2) ? (kptr + c * 4096) : (gkp + (c - 2) * 4096);
            unsigned short* kh = (unsigned short*)base;
            unsigned short* kl = (unsigned short*)(base + 9216);
            f32x4 t[4];
#pragma unroll
            for (int i = 0; i < 4; ++i)
                t[i] = *(const f32x4*)(s + (r0k + i * 16) * 64 + slot * 4);
#pragma unroll
            for (int i = 0; i < 4; ++i) {
                unsigned int h0, l0, h1, l1;
                split2(t[i][0], t[i][1], h0, l0);
                split2(t[i][2], t[i][3], h1, l1);
                int o = (r0k + i * 16) * 72 + slot * 4;
                *reinterpret_cast<uint2*>(kh + o) = make_uint2(h0, h1);
                *reinterpret_cast<uint2*>(kl + o) = make_uint2(l0, l1);
            }
        } else {
            const float* s = (c < 2) ? (vptr + c * 4096) : (gvp + (c - 2) * 4096);
            unsigned short* vb = (unsigned short*)(base + 18432);
            f32x4 t[4];
#pragma unroll
            for (int j = 0; j < 4; ++j)
                t[j] = *(const f32x4*)(s + (key0 + j) * 64 + d0v);
#pragma unroll
            for (int i = 0; i < 4; ++i) {
                unsigned int h0, l0, h1, l1;
                split2(t[0][i], t[1][i], h0, l0);
                split2(t[2][i], t[3][i], h1, l1);
                int o = (d0v + i) * 152 + key0 * 2;
                *reinterpret_cast<uint4*>(vb + o) = make_uint4(h0, h1, l0, l1);
            }
        }
        if (tid < 64) {
            float m = (c < 2) ? amp[c * 64 + tid] : gmp[(c - 2) * 64 + tid];
            *(float*)(base + 37888 + tid * 4) = m * LOG2E;
        }
    };

    const f32x4 zero4 = {0.f, 0.f, 0.f, 0.f};
    f32x4 ctx[4];  // ctx^T[d=dm*16+quad*4+r][q=c15]
#pragma unroll
    for (int dm = 0; dm < 4; ++dm) ctx[dm] = zero4;
    float m_run = -3.4e38f;  // running max, log2 units
    float l_run = 0.f;       // per-lane partial; cross-quad reduce in epilogue

    // ---- compute lambdas (bi = LDS slot index, compile-time post-unroll) ----
    auto qk_compute = [&](int bi, f32x4 (&S)[4]) {
        const unsigned short* k_hi = (const unsigned short*)(lds + bi * SLOT_BYTES);
        const unsigned short* k_lo = (const unsigned short*)(lds + bi * SLOT_BYTES + 9216);
#pragma unroll
        for (int km = 0; km < 4; ++km) S[km] = zero4;
        __builtin_amdgcn_s_setprio(1);
#pragma unroll
        for (int km = 0; km < 4; ++km) {  // pass A: K_hi x (Q_hi, Q_lo)
            int krow = km * 16 + c15;
            bf16x8 kh0 = *(const bf16x8*)(k_hi + krow * 72 + quad * 8);
            bf16x8 kh1 = *(const bf16x8*)(k_hi + krow * 72 + quad * 8 + 32);
            f32x4 a = S[km];
            a = MFMA32(kh0, qbh[0], a);
            a = MFMA32(kh1, qbh[1], a);
            a = MFMA32(kh0, qbl[0], a);
            a = MFMA32(kh1, qbl[1], a);
            S[km] = a;
        }
#pragma unroll
        for (int km = 0; km < 4; ++km) {  // pass B: K_lo x Q_hi
            int krow = km * 16 + c15;
            bf16x8 kl0 = *(const bf16x8*)(k_lo + krow * 72 + quad * 8);
            bf16x8 kl1 = *(const bf16x8*)(k_lo + krow * 72 + quad * 8 + 32);
            f32x4 a = S[km];
            a = MFMA32(kl0, qbh[0], a);
            a = MFMA32(kl1, qbh[1], a);
            S[km] = a;
        }
        __builtin_amdgcn_s_setprio(0);
    };

    auto softmax = [&](int bi, f32x4 (&S)[4], bf16x4 (&ph)[4]) {
        const float* mp = (const float*)(lds + bi * SLOT_BYTES + 37888);
        float pmax = -3.4e38f;
#pragma unroll
        for (int km = 0; km < 4; ++km) {
            f32x4 mkl = *(const f32x4*)(mp + km * 16 + quad * 4);  // transient
#pragma unroll
            for (int r = 0; r < 4; ++r) {
                float s = fmaf(S[km][r], QSCALE, mkl[r]);
                S[km][r] = s;
                pmax = fmaxf(pmax, s);
            }
        }
        if (!__all(pmax <= m_run + DEFER_THR)) {
            float mx = fmaxf(pmax, __shfl_xor(pmax, 16));
            mx = fmaxf(mx, __shfl_xor(mx, 32));
            float mn = fmaxf(m_run, mx);
            float alpha = __builtin_amdgcn_exp2f(m_run - mn);
            m_run = mn;
            l_run *= alpha;
#pragma unroll
            for (int dm = 0; dm < 4; ++dm) {
                ctx[dm][0] *= alpha; ctx[dm][1] *= alpha;
                ctx[dm][2] *= alpha; ctx[dm][3] *= alpha;
            }
        }
        float sm = 0.f;
#pragma unroll
        for (int km = 0; km < 4; ++km) {
#pragma unroll
            for (int r = 0; r < 4; ++r) {
                float e = __builtin_amdgcn_exp2f(S[km][r] - m_run);
                S[km][r] = e;
                sm += e;
            }
            union { bf16x4 b; uint2 u; } P;
            P.u.x = cvt_pk(S[km][0], S[km][1]);
            P.u.y = cvt_pk(S[km][2], S[km][3]);
            ph[km] = P.b;
        }
        l_run += sm;
    };

    auto pv_compute = [&](int bi, const bf16x4 (&ph)[4]) {
        const unsigned int* v_il = (const unsigned int*)(lds + bi * SLOT_BYTES + 18432);
        __builtin_amdgcn_s_setprio(1);
#pragma unroll
        for (int dm = 0; dm < 4; ++dm) {
            int drow = dm * 16 + c15;
            f32x4 a = ctx[dm];
#pragma unroll
            for (int km = 0; km < 4; ++km) {
                uint4 w = *(const uint4*)(v_il + drow * 76 + (km * 4 + quad) * 4);
                union { uint2 u; bf16x4 b; } vh, vl;
                vh.u = make_uint2(w.x, w.y);
                vl.u = make_uint2(w.z, w.w);
                a = MFMA16(vh.b, ph[km], a);
                a = MFMA16(vl.b, ph[km], a);
            }
            ctx[dm] = a;
        }
        __builtin_amdgcn_s_setprio(0);
    };

    // ---- prologue: slot0=chunk0; QK(0) overlaps stage(1)->slot1 ----
    stage(0);
    __syncthreads();
    f32x4 Sb[2][4];
    stage(1);
    qk_compute(0, Sb[0]);
    __syncthreads();  // stage(1) visible to all before iter0's qk(1)

    // ---- main loop: QK(c+1) || softmax(c) -> PV(c) ----
#pragma unroll
    for (int c = 0; c < 4; ++c) {
        if (c < 3) qk_compute((c + 1) & 1, Sb[(c + 1) & 1]);  // indep MFMA

        bf16x4 ph[4];
        softmax(c & 1, Sb[c & 1], ph);  // VALU, interleaves under QK(c+1)
        pv_compute(c & 1, ph);          // MFMA, dep on softmax

        if (c < 2) {
            __syncthreads();   // all reads of slot[c&1] (mask, V) complete
            stage(c + 2);      // chunk c+2 -> slot[(c+2)&1] == slot[c&1]
            __syncthreads();   // visible before iter c+1's qk(c+2)
        }
    }

    // ---- epilogue: reduce l across quads, normalize, bounce through LDS ----
    __syncthreads();  // all waves done with slot reads before o_scr reuse
    {
        float l = l_run;
        l += __shfl_xor(l, 16);
        l += __shfl_xor(l, 32);
        float inv = 1.0f / l;
        int row = wv * 16 + c15;
#pragma unroll
        for (int dm = 0; dm < 4; ++dm) {
            f32x4 o = ctx[dm];
            o[0] *= inv; o[1] *= inv; o[2] *= inv; o[3] *= inv;
            *(f32x4*)(o_scr + row * 68 + dm * 16 + quad * 4) = o;
        }
    }
    __syncthreads();
    {
        float* op = out + ((size_t)bh * Tt + blk * 128) * 64;
        const int oslot = tid & 15, or0 = tid >> 4;
#pragma unroll
        for (int i = 0; i < 4; ++i) {
            int row = or0 + i * 32;
            f32x4 val = *(const f32x4*)(o_scr + row * 68 + oslot * 4);
            *(f32x4*)(op + row * 64 + oslot * 4) = val;
        }
    }
}

extern "C" void kernel_launch(void* const* d_in, const int* in_sizes, int n_in,
                              void* d_out, int out_size, void* d_ws, size_t ws_size,
                              hipStream_t stream) {
    (void)in_sizes; (void)n_in; (void)d_ws; (void)ws_size; (void)out_size;
    const float* q  = (const float*)d_in[0];
    const float* k  = (const float*)d_in[1];
    const float* v  = (const float*)d_in[2];
    const float* am = (const float*)d_in[3];
    const float* gk = (const float*)d_in[4];
    const float* gv = (const float*)d_in[5];
    const float* gm = (const float*)d_in[6];
    dim3 grid(32, 16, 4);
    block_attn_kernel<<<grid, dim3(512), 0, stream>>>(q, k, v, am, gk, gv, gm, (float*)d_out);
}

// Round 8
// 234.053 us; speedup vs baseline: 1.4532x; 1.0720x over previous
//
#include <hip/hip_runtime.h>
#include <hip/hip_bf16.h>

// Flash-style block attention, MI355X gfx950. Round 12.
// Verdict after R7-R11: T15 reorder loses even without spills (R11: 119us,
// both util counters DOWN); 3 WGs/CU unreachable (reg cap 85 spills). R6
// (101us) is the structural optimum: 2 WGs/CU, seq QK->softmax->PV, T14
// early-issue, dbuf + 1 barrier/chunk.
// R12 = R6 minus V_lo, single variable. Rationale: hand-count says LDS is
// the busiest pipe (~45%: 256KB read/WG-chunk + conflicts). ctx is LINEAR
// in V so V-bf16 truncation (~2^-9 rel, ~0.0016 abs) is not exp-amplified;
// V_lo costs 25% of LDS reads, 16 of 48 MFMAs, ~90 staging VALU ops.
//  - V^T single-precision [64][72] hw (9216 B); PV = 16x MFMA16 w/ b64 reads.
//  - V staging: 2x cvt_pk per row (no split2).
//  - Slot = 27648 B, dbuf = 55296 B; all else identical to R6.
// Predicted: dur ~88-91us/dispatch, conflicts 8.65M->~6.5M, absmax ~0.009,
// WRITE=65536 exact, VGPR ~56-60.

typedef __attribute__((ext_vector_type(8))) short bf16x8;
typedef __attribute__((ext_vector_type(4))) short bf16x4;
typedef __attribute__((ext_vector_type(4))) float f32x4;

#define MFMA32(A, B, C) __builtin_amdgcn_mfma_f32_16x16x32_bf16((A), (B), (C), 0, 0, 0)
#define MFMA16(A, B, C) __builtin_amdgcn_mfma_f32_16x16x16bf16_1k((A), (B), (C), 0, 0, 0)

__device__ __forceinline__ unsigned int cvt_pk(float a, float b) {
    __hip_bfloat162 h = __float22bfloat162_rn(float2{a, b});
    union { __hip_bfloat162 h; unsigned int u; } c;
    c.h = h;
    return c.u;
}
__device__ __forceinline__ void split2(float a, float b, unsigned int& hi, unsigned int& lo) {
    unsigned int h = cvt_pk(a, b);
    float ra = a - __uint_as_float(h << 16);
    float rb = b - __uint_as_float(h & 0xFFFF0000u);
    hi = h;
    lo = cvt_pk(ra, rb);
}
__device__ __forceinline__ void split8v(f32x4 a, f32x4 b, bf16x8& hi, bf16x8& lo) {
    union { bf16x8 v; unsigned int w[4]; } H, L;
    split2(a[0], a[1], H.w[0], L.w[0]);
    split2(a[2], a[3], H.w[1], L.w[1]);
    split2(b[0], b[1], H.w[2], L.w[2]);
    split2(b[2], b[3], H.w[3], L.w[3]);
    hi = H.v; lo = L.v;
}

// Per-buffer layout: K_hi [64][72] hw (9216 B) | K_lo [64][72] hw (9216 B) |
// V^T hi [64][72] hw (9216 B) = 27648 B. Two buffers = 55296 B.
// Epilogue reuses bytes [0,34816) as [128][68] f32.
#define BUF_BYTES 27648

#define LOG2E 1.44269504f
#define QSCALE 0.180336880f  /* 0.125 * log2(e) */
#define DEFER_THR 8.0f

__global__ __launch_bounds__(512, 4) void block_attn_kernel(
    const float* __restrict__ q, const float* __restrict__ k,
    const float* __restrict__ v, const float* __restrict__ amask,
    const float* __restrict__ gk, const float* __restrict__ gv,
    const float* __restrict__ gmask, float* __restrict__ out) {
    constexpr int Hh = 16, Tt = 4096, Gg = 128;

    __shared__ __align__(16) unsigned char lds[2 * BUF_BYTES];
    float* o_scr = (float*)lds;  // [128][68] epilogue scratch

    const int blk = blockIdx.x;
    const int bh  = blockIdx.z * Hh + blockIdx.y;
    const int tid  = threadIdx.x;
    const int lane = tid & 63;
    const int wv   = tid >> 6;      // 0..7, wave owns q-rows [wv*16, wv*16+16)
    const int c15  = lane & 15;
    const int quad = lane >> 4;

    const float* qptr = q + ((size_t)bh * Tt + blk * 128) * 64;
    const float* kptr = k + ((size_t)bh * Tt + blk * 128) * 64;
    const float* vptr = v + ((size_t)bh * Tt + blk * 128) * 64;
    const float* gkp  = gk + (size_t)bh * Gg * 64;
    const float* gvp  = gv + (size_t)bh * Gg * 64;
    const float* amp  = amask + (size_t)bh * Tt + blk * 128;
    const float* gmp  = gmask + (size_t)bh * Gg;

    // ---- Q as B-operand frags: n=c15 (q-row), k=d=32*half+quad*8+j ----
    bf16x8 qbh[2], qbl[2];
    {
        int row = wv * 16 + c15;
#pragma unroll
        for (int h = 0; h < 2; ++h) {
            f32x4 a = *(const f32x4*)(qptr + row * 64 + h * 32 + quad * 8);
            f32x4 b = *(const f32x4*)(qptr + row * 64 + h * 32 + quad * 8 + 4);
            split8v(a, b, qbh[h], qbl[h]);
        }
    }

    // ---- staging geometry (waves 0-3: K chunk; waves 4-7: V^T chunk) ----
    const int slot = tid & 15;
    const int r0k  = (tid >> 4) & 15;
    const int tV   = tid & 255;            // tid-256 for waves 4-7
    const int key0 = 4 * (tV & 15);
    const int d0v  = 4 * ((tV >> 4) & 3) + 16 * (tV >> 6);

    int soff[4];
    const float *sloc, *sglb;
    if (wv < 4) {
        sloc = kptr; sglb = gkp;
#pragma unroll
        for (int i = 0; i < 4; ++i) soff[i] = (r0k + i * 16) * 64 + slot * 4;
    } else {
        sloc = vptr; sglb = gvp;
#pragma unroll
        for (int j = 0; j < 4; ++j) soff[j] = (key0 + j) * 64 + d0v;
    }

    f32x4 stg[4];
    auto stage_load = [&](int c) {
        const float* s = (c < 2) ? (sloc + c * 4096) : (sglb + (c - 2) * 4096);
#pragma unroll
        for (int j = 0; j < 4; ++j) stg[j] = *(const f32x4*)(s + soff[j]);
    };
    auto stage_store = [&](int b) {
        unsigned char* base = lds + b * BUF_BYTES;
        if (wv < 4) {
            unsigned short* kh = (unsigned short*)base;
            unsigned short* kl = (unsigned short*)(base + 9216);
#pragma unroll
            for (int i = 0; i < 4; ++i) {
                unsigned int h0, l0, h1, l1;
                split2(stg[i][0], stg[i][1], h0, l0);
                split2(stg[i][2], stg[i][3], h1, l1);
                int o = (r0k + i * 16) * 72 + slot * 4;
                *reinterpret_cast<uint2*>(kh + o) = make_uint2(h0, h1);
                *reinterpret_cast<uint2*>(kl + o) = make_uint2(l0, l1);
            }
        } else {
            unsigned short* vb = (unsigned short*)(base + 18432);
#pragma unroll
            for (int i = 0; i < 4; ++i) {
                unsigned int h0 = cvt_pk(stg[0][i], stg[1][i]);
                unsigned int h1 = cvt_pk(stg[2][i], stg[3][i]);
                int o = (d0v + i) * 72 + key0;
                *reinterpret_cast<uint2*>(vb + o) = make_uint2(h0, h1);
            }
        }
    };

    // ---- prologue: fill buffer 0 with chunk 0 ----
    stage_load(0);
    stage_store(0);
    __syncthreads();

    const f32x4 zero4 = {0.f, 0.f, 0.f, 0.f};
    f32x4 ctx[4];  // ctx^T[d=dm*16+quad*4+r][q=c15]
#pragma unroll
    for (int dm = 0; dm < 4; ++dm) ctx[dm] = zero4;
    float m_run = -3.4e38f;  // running max, log2 units
    float l_run = 0.f;       // per-lane partial; cross-quad reduce in epilogue

#pragma unroll
    for (int c = 0; c < 4; ++c) {
        // masks for THIS chunk, vectorized; issued before the stage prefetch
        // so their vmcnt wait cannot drain the prefetch behind them.
        const float* mb = (c < 2) ? (amp + c * 64) : (gmp + (c - 2) * 64);
        f32x4 mkl[4];
#pragma unroll
        for (int km = 0; km < 4; ++km) {
            f32x4 m = *(const f32x4*)(mb + km * 16 + quad * 4);
            mkl[km] = m * LOG2E;  // log2 domain
        }

        // T14 issue-early: next chunk's global loads in flight during compute
        if (c < 3) stage_load(c + 1);

        unsigned char* rb = lds + (c & 1) * BUF_BYTES;
        const unsigned short* k_hi = (const unsigned short*)rb;
        const unsigned short* k_lo = (const unsigned short*)(rb + 9216);
        const unsigned short* v_hi = (const unsigned short*)(rb + 18432);

        // ---- S^T = K·Q^T : D[m=key=km*16+quad*4+r][n=q=c15] ----
        f32x4 S[4];
#pragma unroll
        for (int km = 0; km < 4; ++km) S[km] = zero4;

        __builtin_amdgcn_s_setprio(1);
#pragma unroll
        for (int km = 0; km < 4; ++km) {
            int krow = km * 16 + c15;
            bf16x8 kh0 = *(const bf16x8*)(k_hi + krow * 72 + quad * 8);
            bf16x8 kh1 = *(const bf16x8*)(k_hi + krow * 72 + quad * 8 + 32);
            bf16x8 kl0 = *(const bf16x8*)(k_lo + krow * 72 + quad * 8);
            bf16x8 kl1 = *(const bf16x8*)(k_lo + krow * 72 + quad * 8 + 32);
            f32x4 a = S[km];
            a = MFMA32(kh0, qbh[0], a);
            a = MFMA32(kh1, qbh[1], a);
            a = MFMA32(kh0, qbl[0], a);
            a = MFMA32(kh1, qbl[1], a);
            a = MFMA32(kl0, qbh[0], a);
            a = MFMA32(kl1, qbh[1], a);
            S[km] = a;
        }
        __builtin_amdgcn_s_setprio(0);

        // ---- online softmax, log2 domain, deferred max + deferred sum ----
        bf16x4 ph[4];
        {
            float pmax = -3.4e38f;
#pragma unroll
            for (int km = 0; km < 4; ++km)
#pragma unroll
                for (int r = 0; r < 4; ++r) {
                    float s = fmaf(S[km][r], QSCALE, mkl[km][r]);
                    S[km][r] = s;
                    pmax = fmaxf(pmax, s);
                }
            if (!__all(pmax <= m_run + DEFER_THR)) {
                float mx = fmaxf(pmax, __shfl_xor(pmax, 16));
                mx = fmaxf(mx, __shfl_xor(mx, 32));
                float mn = fmaxf(m_run, mx);
                float alpha = __builtin_amdgcn_exp2f(m_run - mn);
                m_run = mn;
                l_run *= alpha;
#pragma unroll
                for (int dm = 0; dm < 4; ++dm) {
                    ctx[dm][0] *= alpha; ctx[dm][1] *= alpha;
                    ctx[dm][2] *= alpha; ctx[dm][3] *= alpha;
                }
            }
            float sm = 0.f;
#pragma unroll
            for (int km = 0; km < 4; ++km) {
#pragma unroll
                for (int r = 0; r < 4; ++r) {
                    float e = __builtin_amdgcn_exp2f(S[km][r] - m_run);
                    S[km][r] = e;
                    sm += e;
                }
                union { bf16x4 b; uint2 u; } P;
                P.u.x = cvt_pk(S[km][0], S[km][1]);
                P.u.y = cvt_pk(S[km][2], S[km][3]);
                ph[km] = P.b;
            }
            l_run += sm;  // per-lane partial; cross-quad reduce in epilogue
        }

        // ---- ctx^T += V^T_hi · P^T (mfma 16x16x16, 16 MFMAs) ----
        __builtin_amdgcn_s_setprio(1);
#pragma unroll
        for (int dm = 0; dm < 4; ++dm) {
            int drow = dm * 16 + c15;
            f32x4 a = ctx[dm];
#pragma unroll
            for (int km = 0; km < 4; ++km) {
                bf16x4 vh = *(const bf16x4*)(v_hi + drow * 72 + km * 16 + quad * 4);
                a = MFMA16(vh, ph[km], a);
            }
            ctx[dm] = a;
        }
        __builtin_amdgcn_s_setprio(0);

        // convert+write NEXT chunk into the other buffer (T14 write-late)
        if (c < 3) stage_store((c + 1) & 1);
        __syncthreads();
    }

    // ---- epilogue: reduce l across quads, normalize, bounce through LDS ----
    {
        float l = l_run;
        l += __shfl_xor(l, 16);
        l += __shfl_xor(l, 32);
        float inv = 1.0f / l;
        int row = wv * 16 + c15;
#pragma unroll
        for (int dm = 0; dm < 4; ++dm) {
            f32x4 o = ctx[dm];
            o[0] *= inv; o[1] *= inv; o[2] *= inv; o[3] *= inv;
            *(f32x4*)(o_scr + row * 68 + dm * 16 + quad * 4) = o;
        }
    }
    __syncthreads();
    {
        float* op = out + ((size_t)bh * Tt + blk * 128) * 64;
        const int oslot = tid & 15, or0 = tid >> 4;  // or0 0..31
#pragma unroll
        for (int i = 0; i < 4; ++i) {
            int row = or0 + i * 32;
            f32x4 val = *(const f32x4*)(o_scr + row * 68 + oslot * 4);
            *(f32x4*)(op + row * 64 + oslot * 4) = val;
        }
    }
}

extern "C" void kernel_launch(void* const* d_in, const int* in_sizes, int n_in,
                              void* d_out, int out_size, void* d_ws, size_t ws_size,
                              hipStream_t stream) {
    (void)in_sizes; (void)n_in; (void)d_ws; (void)ws_size; (void)out_size;
    const float* q  = (const float*)d_in[0];
    const float* k  = (const float*)d_in[1];
    const float* v  = (const float*)d_in[2];
    const float* am = (const float*)d_in[3];
    const float* gk = (const float*)d_in[4];
    const float* gv = (const float*)d_in[5];
    const float* gm = (const float*)d_in[6];
    dim3 grid(32, 16, 4);
    block_attn_kernel<<<grid, dim3(512), 0, stream>>>(q, k, v, am, gk, gv, gm, (float*)d_out);
}